// Round 7
// baseline (152.724 us; speedup 1.0000x reference)
//
#include <hip/hip_runtime.h>
#include <math.h>

// Problem constants: B,H,K,L,V = 4096,1024,10,64,80
constexpr int Bn = 4096;
constexpr int Hn = 1024;
constexpr int Kn = 10;
constexpr int Ln = 64;
constexpr int Vn = 80;
constexpr int NJ = 3 * Kn;   // 30
constexpr int R  = 4;        // batch rows per block
constexpr int NT = 256;

// R0's proven fused structure with one change: the einsum finishes in-wave
// (one wave per row, shuffle reduce) instead of via a 15.4 KB cpart LDS
// round-trip. LDS 37 KB -> 21.5 KB => 7 blocks/CU (28 waves/CU vs 16).
// __launch_bounds__(256,7) pins VGPR <= ~72 so the allocator honors it.
__global__ __launch_bounds__(NT, 7) void window_fused(
    const float* __restrict__ x,      // [B,H]
    const float* __restrict__ chars,  // [B,L,V]
    const float* __restrict__ W,      // [H,3K]
    const float* __restrict__ bias,   // [3K]
    float* __restrict__ out)          // [B,V]
{
    __shared__ float4 xs4[R * Hn / 4];   // 16 KB
    __shared__ float  part[R * 256];     // 4 KB  (r, g*32+j) — proven conflict-free
    __shared__ float  abk[R * NJ];       // 480 B
    __shared__ float  phi_s[R * Ln];     // 1 KB

    const int t    = threadIdx.x;
    const int row0 = blockIdx.x * R;

    // ---- Stage x rows into LDS (coalesced float4) ----
    const float4* xg4 = (const float4*)x + (size_t)row0 * (Hn / 4);
#pragma unroll
    for (int r = 0; r < R; ++r)
        xs4[r * (Hn / 4) + t] = xg4[r * (Hn / 4) + t];
    __syncthreads();

    // ---- GEMM partials: part[r][g*32+j] = sum_{h in g's 128} x[r][h]*W[h][j] ----
    const int j = t & 31;
    const int g = t >> 5;
    float acc0 = 0.f, acc1 = 0.f, acc2 = 0.f, acc3 = 0.f;
    if (j < NJ) {
        const float* Wp = W + j;
        const int h0 = g * 128;
#pragma unroll 4
        for (int ii = 0; ii < 128; ii += 4) {
            const int h  = h0 + ii;
            const int h4 = h >> 2;
            float4 xa = xs4[0 * (Hn / 4) + h4];   // LDS broadcast across j-lanes
            float4 xb = xs4[1 * (Hn / 4) + h4];
            float4 xc = xs4[2 * (Hn / 4) + h4];
            float4 xd = xs4[3 * (Hn / 4) + h4];
            float w0 = Wp[(h + 0) * NJ];
            float w1 = Wp[(h + 1) * NJ];
            float w2 = Wp[(h + 2) * NJ];
            float w3 = Wp[(h + 3) * NJ];
            acc0 += w0 * xa.x + w1 * xa.y + w2 * xa.z + w3 * xa.w;
            acc1 += w0 * xb.x + w1 * xb.y + w2 * xb.z + w3 * xb.w;
            acc2 += w0 * xc.x + w1 * xc.y + w2 * xc.z + w3 * xc.w;
            acc3 += w0 * xd.x + w1 * xd.y + w2 * xd.z + w3 * xd.w;
        }
    }
    part[0 * 256 + g * 32 + j] = acc0;
    part[1 * 256 + g * 32 + j] = acc1;
    part[2 * 256 + g * 32 + j] = acc2;
    part[3 * 256 + g * 32 + j] = acc3;
    __syncthreads();

    // ---- Reduce partials + bias, exp -> alpha/beta/kappa ----
    if (t < R * NJ) {  // 120 threads
        const int r = t / NJ, jj = t % NJ;
        float s = bias[jj];
#pragma unroll
        for (int gg = 0; gg < 8; ++gg) s += part[r * 256 + gg * 32 + jj];
        abk[r * NJ + jj] = __expf(s);
    }
    __syncthreads();

    // ---- phi[r][l] = sum_k alpha * exp(-beta*(kappa-l)^2) ----
    {
        const int r = t >> 6, l = t & 63;
        const float lf = (float)l;
        const float* ab = abk + r * NJ;
        float ph = 0.f;
#pragma unroll
        for (int k = 0; k < Kn; ++k) {
            float a  = ab[k];
            float bt = ab[Kn + k];
            float kp = ab[2 * Kn + k];
            float d  = kp - lf;
            ph += a * __expf(-bt * d * d);
        }
        phi_s[r * Ln + l] = ph;
    }
    __syncthreads();

    // ---- Einsum, one wave per row (proven lane map from R6-K2):
    //      ll<60: ls=ll/20 picks l in {ls, ls+3, ...}, v4=ll%20 picks column.
    //      Wave reads 960 B contiguous per iteration; 22 independent loads.
    const int lane = t & 63;
    const int rr   = t >> 6;          // wave id == row within block
    const int ll = (lane < 60) ? lane : lane - 60;   // lanes 60-63 duplicate
    const int ls = ll / 20;
    const int v4 = ll % 20;

    const float4* cb = (const float4*)chars + (size_t)(row0 + rr) * (Ln * Vn / 4);
    const float*  ph = phi_s + rr * Ln;

    float4 acc = make_float4(0.f, 0.f, 0.f, 0.f);
#pragma unroll
    for (int i = 0; i < 22; ++i) {
        const int l = ls + 3 * i;
        if (l < Ln) {
            float4 c = cb[l * (Vn / 4) + v4];
            float  p = ph[l];         // LDS broadcast (3 addrs/wave)
            acc.x += p * c.x; acc.y += p * c.y;
            acc.z += p * c.z; acc.w += p * c.w;
        }
    }

    // reduce the 3 l-subsets: lanes 0-19 pull from +20 (ls=1) and +40 (ls=2)
    acc.x += __shfl(acc.x, lane + 20) + __shfl(acc.x, lane + 40);
    acc.y += __shfl(acc.y, lane + 20) + __shfl(acc.y, lane + 40);
    acc.z += __shfl(acc.z, lane + 20) + __shfl(acc.z, lane + 40);
    acc.w += __shfl(acc.w, lane + 20) + __shfl(acc.w, lane + 40);

    if (lane < 20)
        ((float4*)out)[(size_t)(row0 + rr) * (Vn / 4) + lane] = acc;  // 320 B
}

extern "C" void kernel_launch(void* const* d_in, const int* in_sizes, int n_in,
                              void* d_out, int out_size, void* d_ws, size_t ws_size,
                              hipStream_t stream) {
    const float* x     = (const float*)d_in[0];
    const float* chars = (const float*)d_in[1];
    const float* W     = (const float*)d_in[2];
    const float* bias  = (const float*)d_in[3];
    float* out = (float*)d_out;

    window_fused<<<Bn / R, NT, 0, stream>>>(x, chars, W, bias, out);
}